// Round 9
// baseline (51.696 us; speedup 1.0000x reference)
//
#include <hip/hip_runtime.h>

#define NN 128
#define CCH 16
#define BB 4
#define HID 128
#define DOUT 128

// ws float offsets
#define XT_OFF  0u           // [b][c][128][128] transpose (4 MiB)
#define XD_OFF  1048576u     // [b][c][128] diagonals
#define WD_OFF  1056768u     // [128][8] packed MLP weights
#define H1_OFF  2097152u     // [b][c][p][q] h1 values (4 MiB)
#define DG_OFF  3145728u     // [b][c][p][qh] diag partials

// ---------------------------------------------------------------------------
// xpose_prep: per (b,c,32-row stripe): coalesced transpose -> xT, diag -> xd.
// Block 0 also packs MLP weights into wd[k][8] = {W1[k][0..3], b1, W2[0][k],
// W2[1][k], 0}. (Validated since round 4.)
// ---------------------------------------------------------------------------
__global__ __launch_bounds__(512) void xpose_prep(
    const float* __restrict__ x,
    const float* __restrict__ W1, const float* __restrict__ b1,
    const float* __restrict__ W2, float* __restrict__ ws)
{
    __shared__ float tile[32][NN + 1];
    const int t   = threadIdx.x;
    const int bid = blockIdx.x;
    const int st  = bid & 3;
    const int c   = (bid >> 2) & 15;
    const int b   = bid >> 6;
    const int q0  = st * 32;
    const float* xm = x + ((size_t)(b * CCH + c) << 14);
    float* xT = ws + XT_OFF;
    float* xd = ws + XD_OFF;

    if (bid == 0 && t < HID) {
        const float4 w = reinterpret_cast<const float4*>(W1)[t];
        float* wd = ws + WD_OFF + t * 8;
        wd[0] = w.x; wd[1] = w.y; wd[2] = w.z; wd[3] = w.w;
        wd[4] = b1[t]; wd[5] = W2[t]; wd[6] = W2[HID + t]; wd[7] = 0.f;
    }

    #pragma unroll
    for (int pass = 0; pass < 2; ++pass) {
        const int i = (t >> 5) + pass * 16;
        const int m = (t & 31) * 4;
        const float4 v = *reinterpret_cast<const float4*>(&xm[(q0 + i) * NN + m]);
        tile[i][m] = v.x; tile[i][m+1] = v.y; tile[i][m+2] = v.z; tile[i][m+3] = v.w;
    }
    __syncthreads();
    if (t < 32) xd[(b * CCH + c) * NN + q0 + t] = tile[t][q0 + t];
    float* xTm = xT + ((size_t)(b * CCH + c) << 14);
    const int p = t >> 2;
    #pragma unroll
    for (int g = 0; g < 2; ++g) {
        const int qq = (t & 3) * 8 + g * 4;
        float4 v;
        v.x = tile[qq+0][p]; v.y = tile[qq+1][p]; v.z = tile[qq+2][p]; v.w = tile[qq+3][p];
        *reinterpret_cast<float4*>(&xTm[p * NN + q0 + qq]) = v;
    }
}

// ---------------------------------------------------------------------------
// k1: block = (b, p, q-half), 256 threads = 4 waves. NO LDS, NO barriers.
// Thread (c = t>>4, qg = t&15) handles channel c, q = qh*64 + qg*4 .. +3.
// Per k: a = W1[k][0]*x_pp + b1[k] amortized over 4 q's -> 6.25 ops/cell.
// Weights via uniform float4 loads of packed wd (scalarized to s_load).
// h1 (+b2[1]) -> ws float4; diag partial via width-16 shuffle -> ws.
// ---------------------------------------------------------------------------
__global__ __launch_bounds__(256) void k1_mlp(
    const float* __restrict__ x, const float* __restrict__ xT,
    const float* __restrict__ xd, const float* __restrict__ wd,
    const float* __restrict__ b2,
    float* __restrict__ h1w, float* __restrict__ dgw)
{
    const int t   = threadIdx.x;
    const int bid = blockIdx.x;
    const int qh  = bid & 1;
    const int p   = (bid >> 1) & 127;
    const int b   = bid >> 8;
    const int c   = t >> 4;            // 0..15
    const int qg  = t & 15;
    const int q0  = qh * 64 + qg * 4;

    const float4* wd4 = reinterpret_cast<const float4*>(wd);
    const size_t mbase = (size_t)(b * CCH + c) << 14;
    const int    dbase = (b * CCH + c) * NN;

    const float4 vpq = *reinterpret_cast<const float4*>(&x [mbase + p * NN + q0]);
    const float4 vqp = *reinterpret_cast<const float4*>(&xT[mbase + p * NN + q0]);
    const float4 vqq = *reinterpret_cast<const float4*>(&xd[dbase + q0]);
    const float  xpp = xd[dbase + p];

    const float xpq[4] = { vpq.x, vpq.y, vpq.z, vpq.w };
    const float xqp[4] = { vqp.x, vqp.y, vqp.z, vqp.w };
    const float xqq[4] = { vqq.x, vqq.y, vqq.z, vqq.w };

    float h0[4] = { 0.f, 0.f, 0.f, 0.f };
    float h1[4] = { 0.f, 0.f, 0.f, 0.f };

    #pragma unroll 4
    for (int k = 0; k < HID; ++k) {
        const float4 wA = wd4[2 * k];        // w0 w1 w2 w3  (uniform -> s_load)
        const float4 wB = wd4[2 * k + 1];    // b1 w20 w21 -
        const float a = fmaf(wA.x, xpp, wB.x);   // q-invariant
        #pragma unroll
        for (int j = 0; j < 4; ++j) {
            float hd = fmaf(wA.y, xpq[j], a);
            hd = fmaf(wA.z, xqp[j], hd);
            hd = fmaf(wA.w, xqq[j], hd);
            hd = fmaxf(hd, 0.f);
            h0[j] = fmaf(wB.y, hd, h0[j]);
            h1[j] = fmaf(wB.z, hd, h1[j]);
        }
    }

    const float bb1 = b2[1];
    float4 o;
    o.x = h1[0] + bb1; o.y = h1[1] + bb1; o.z = h1[2] + bb1; o.w = h1[3] + bb1;
    *reinterpret_cast<float4*>(&h1w[((size_t)dbase + p) * NN + q0]) = o;

    // diag partial: mask q==p, reduce over the 16 threads sharing c
    float s = 0.f;
    #pragma unroll
    for (int j = 0; j < 4; ++j)
        s += (q0 + j == p) ? 0.f : h0[j];
    #pragma unroll
    for (int off = 8; off > 0; off >>= 1)
        s += __shfl_down(s, off, 16);
    if (qg == 0) dgw[(dbase + p) * 2 + qh] = s;
}

// ---------------------------------------------------------------------------
// k2: block = (b, p), 256 threads = 4 waves. Stage h1 row + diag fix in LDS,
// then channel mix 16->128 + ReLU, streamed to y. Wave handles 32 d's
// (wave-uniform -> scalar Wc/bc loads), lane covers an m-pair.
// ---------------------------------------------------------------------------
__global__ __launch_bounds__(256) void k2_mix(
    const float* __restrict__ h1w, const float* __restrict__ dgw,
    const float* __restrict__ b2,
    const float* __restrict__ Wc, const float* __restrict__ bc,
    float* __restrict__ y)
{
    __shared__ float s_out[CCH][NN];   // 8 KB
    const int t   = threadIdx.x;
    const int bid = blockIdx.x;
    const int p   = bid & 127;
    const int b   = bid >> 7;

    #pragma unroll
    for (int i = 0; i < 2; ++i) {
        const int idx = t + i * 256;           // 512 float4s = 16x128
        const int c  = idx >> 5;
        const int mq = (idx & 31) * 4;
        *reinterpret_cast<float4*>(&s_out[c][mq]) =
            *reinterpret_cast<const float4*>(
                &h1w[((size_t)(b * CCH + c) * NN + p) * NN + mq]);
    }
    __syncthreads();
    if (t < CCH) {
        const int dbase = (b * CCH + t) * NN;
        const float d0 = dgw[(dbase + p) * 2 + 0];
        const float d1 = dgw[(dbase + p) * 2 + 1];
        s_out[t][p] = (d0 + d1) * (1.0f / (NN - 1)) + b2[0];
    }
    __syncthreads();

    const int wv = t >> 6;             // 0..3 -> 32 d's each
    const int m0 = (t & 63) * 2;
    float rx[CCH], ry[CCH];
    #pragma unroll
    for (int cc = 0; cc < CCH; ++cc) {
        const float2 rv = *reinterpret_cast<const float2*>(&s_out[cc][m0]);
        rx[cc] = rv.x; ry[cc] = rv.y;
    }

    #pragma unroll 4
    for (int dd = 0; dd < 32; ++dd) {
        const int d = wv * 32 + dd;        // wave-uniform
        const float bcv = bc[d];           // scalar load
        float ax = bcv, ay = bcv;
        #pragma unroll
        for (int cc = 0; cc < CCH; ++cc) {
            const float wcf = Wc[d * CCH + cc];   // scalar load
            ax = fmaf(wcf, rx[cc], ax);
            ay = fmaf(wcf, ry[cc], ay);
        }
        float2 ov;
        ov.x = fmaxf(ax, 0.f);
        ov.y = fmaxf(ay, 0.f);
        *reinterpret_cast<float2*>(
            &y[(((size_t)(b * DOUT + d)) * NN + p) * NN + m0]) = ov;
    }
}

extern "C" void kernel_launch(void* const* d_in, const int* in_sizes, int n_in,
                              void* d_out, int out_size, void* d_ws, size_t ws_size,
                              hipStream_t stream) {
    const float* x  = (const float*)d_in[0];
    const float* W1 = (const float*)d_in[1];
    const float* b1 = (const float*)d_in[2];
    const float* W2 = (const float*)d_in[3];
    const float* b2 = (const float*)d_in[4];
    const float* Wc = (const float*)d_in[5];
    const float* bc = (const float*)d_in[6];
    float* y  = (float*)d_out;
    float* ws = (float*)d_ws;

    float* xT  = ws + XT_OFF;
    float* xd  = ws + XD_OFF;
    float* wd  = ws + WD_OFF;
    float* h1w = ws + H1_OFF;
    float* dgw = ws + DG_OFF;

    xpose_prep<<<dim3(BB * CCH * 4), 512, 0, stream>>>(x, W1, b1, W2, ws);
    k1_mlp<<<dim3(BB * NN * 2), 256, 0, stream>>>(x, xT, xd, wd, b2, h1w, dgw);
    k2_mix<<<dim3(BB * NN), 256, 0, stream>>>(h1w, dgw, b2, Wc, bc, y);
}